// Round 1
// 1413.338 us; speedup vs baseline: 1.1051x; 1.1051x over previous
//
#include <hip/hip_runtime.h>
#include <math.h>

#define H 64
#define N 50
#define S 50
#define B 1024
#define V 200000
#define VO (V - 1)   // 199999 output columns

// ---------------------------------------------------------------------------
// K1: h0 = emb[items]; hv_in = h0@ein_w + ein_b; hv_out = h0@eou_w + eou_b
// 256 threads = 4 waves; block handles 32 rows (8 rows per wave, register-
// blocked) so each weight element loaded once per 8 rows instead of per row.
// grid = B*N/32 = 1600
// ---------------------------------------------------------------------------
__global__ __launch_bounds__(256) void k1_embed_lin(
    const int* __restrict__ items, const float* __restrict__ emb,
    const float* __restrict__ ein_w, const float* __restrict__ ein_b,
    const float* __restrict__ eou_w, const float* __restrict__ eou_b,
    float* __restrict__ h0, float* __restrict__ hv_in, float* __restrict__ hv_out)
{
    int tid = threadIdx.x;
    int j = tid & 63, w = tid >> 6;
    int bn0 = blockIdx.x * 32;
    __shared__ __align__(16) float hs[32][H];   // 8 KB

    for (int idx = tid; idx < 32 * H; idx += 256) {
        int row = idx >> 6, col = idx & 63;
        int item = items[bn0 + row];
        float hv = emb[(size_t)item * H + col];
        hs[row][col] = hv;
        h0[(size_t)(bn0 + row) * H + col] = hv;
    }
    __syncthreads();

    float accI[8], accO[8];
    {
        float bi = ein_b[j], bo = eou_b[j];
        #pragma unroll
        for (int r = 0; r < 8; r++) { accI[r] = bi; accO[r] = bo; }
    }
    int base = w * 8;
    #pragma unroll 4
    for (int k4 = 0; k4 < 16; k4++) {
        float4 xv[8];
        #pragma unroll
        for (int r = 0; r < 8; r++)
            xv[r] = *(const float4*)&hs[base + r][k4 * 4];  // broadcast, free
        #pragma unroll
        for (int kk = 0; kk < 4; kk++) {
            int k = k4 * 4 + kk;
            float wi = ein_w[k * H + j];   // coalesced 256B across lanes
            float wo = eou_w[k * H + j];
            #pragma unroll
            for (int r = 0; r < 8; r++) {
                float x = ((const float*)&xv[r])[kk];
                accI[r] += x * wi;
                accO[r] += x * wo;
            }
        }
    }
    #pragma unroll
    for (int r = 0; r < 8; r++) {
        hv_in [(size_t)(bn0 + base + r) * H + j] = accI[r];
        hv_out[(size_t)(bn0 + base + r) * H + j] = accO[r];
    }
}

// ---------------------------------------------------------------------------
// K2: input_in = ain @ hv_in + b_iah ; input_out = aou @ hv_out + b_oah
// One block per batch: hv_in/hv_out[b] staged in LDS once (was re-read by
// all N row-blocks), ain/aou each read exactly once from HBM.
// grid = B
// ---------------------------------------------------------------------------
__global__ __launch_bounds__(256) void k2_adj(
    const float* __restrict__ ain, const float* __restrict__ aou,
    const float* __restrict__ hv_in, const float* __restrict__ hv_out,
    const float* __restrict__ b_iah, const float* __restrict__ b_oah,
    float* __restrict__ in_in, float* __restrict__ in_out)
{
    int tid = threadIdx.x;
    int j = tid & 63, w = tid >> 6;
    int b = blockIdx.x;
    __shared__ float hin_s[N][H];   // 12.8 KB
    __shared__ float hou_s[N][H];   // 12.8 KB

    for (int idx = tid; idx < N * H; idx += 256) {
        int row = idx >> 6, col = idx & 63;
        hin_s[row][col] = hv_in [((size_t)b * N + row) * H + col];
        hou_s[row][col] = hv_out[((size_t)b * N + row) * H + col];
    }
    __syncthreads();

    float bi = b_iah[j], bo = b_oah[j];
    for (int n = w; n < N; n += 4) {
        const float* ar = ain + ((size_t)b * N + n) * N;
        const float* br = aou + ((size_t)b * N + n) * N;
        float si = bi, so = bo;
        for (int m = 0; m < N; m++) {
            si += ar[m] * hin_s[m][j];
            so += br[m] * hou_s[m][j];
        }
        in_in [((size_t)b * N + n) * H + j] = si;
        in_out[((size_t)b * N + n) * H + j] = so;
    }
}

// ---------------------------------------------------------------------------
// K3: GRU gates. 4 waves x 8 rows register-blocked: igate_w/hgate_w (147 KB,
// previously re-read per wave -> 7.5 GB L2) now amortized 8x. In-place h0.
// grid = B*N/32 = 1600
// ---------------------------------------------------------------------------
__global__ __launch_bounds__(256) void k3_gru(
    const float* __restrict__ in_in, const float* __restrict__ in_out,
    const float* __restrict__ igate_w, const float* __restrict__ igate_b,
    const float* __restrict__ hgate_w, const float* __restrict__ hgate_b,
    float* __restrict__ h0)
{
    int tid = threadIdx.x;
    int j = tid & 63, w = tid >> 6;
    int bn0 = blockIdx.x * 32;
    __shared__ __align__(16) float inp_s[32][2 * H];   // 16 KB
    __shared__ __align__(16) float h_s[32][H];         // 8 KB

    for (int idx = tid; idx < 32 * H; idx += 256) {
        int row = idx >> 6, col = idx & 63;
        size_t g = (size_t)(bn0 + row) * H + col;
        inp_s[row][col]     = in_in[g];
        inp_s[row][H + col] = in_out[g];
        h_s[row][col]       = h0[g];
    }
    __syncthreads();

    int base = w * 8;
    float gr[8], gi[8], gn[8];
    {
        float b0v = igate_b[j], b1v = igate_b[H + j], b2v = igate_b[2 * H + j];
        #pragma unroll
        for (int r = 0; r < 8; r++) { gr[r] = b0v; gi[r] = b1v; gn[r] = b2v; }
    }
    #pragma unroll 2
    for (int k4 = 0; k4 < 32; k4++) {          // 2H = 128 k's
        float4 xv[8];
        #pragma unroll
        for (int r = 0; r < 8; r++)
            xv[r] = *(const float4*)&inp_s[base + r][k4 * 4];
        #pragma unroll
        for (int kk = 0; kk < 4; kk++) {
            int k = k4 * 4 + kk;
            const float* wrow = igate_w + (size_t)k * 3 * H;
            float w0 = wrow[j], w1 = wrow[H + j], w2 = wrow[2 * H + j];
            #pragma unroll
            for (int r = 0; r < 8; r++) {
                float x = ((const float*)&xv[r])[kk];
                gr[r] += x * w0; gi[r] += x * w1; gn[r] += x * w2;
            }
        }
    }
    float hr[8], hi[8], hn[8];
    {
        float b0v = hgate_b[j], b1v = hgate_b[H + j], b2v = hgate_b[2 * H + j];
        #pragma unroll
        for (int r = 0; r < 8; r++) { hr[r] = b0v; hi[r] = b1v; hn[r] = b2v; }
    }
    #pragma unroll 2
    for (int k4 = 0; k4 < 16; k4++) {          // H = 64 k's
        float4 xv[8];
        #pragma unroll
        for (int r = 0; r < 8; r++)
            xv[r] = *(const float4*)&h_s[base + r][k4 * 4];
        #pragma unroll
        for (int kk = 0; kk < 4; kk++) {
            int k = k4 * 4 + kk;
            const float* wrow = hgate_w + (size_t)k * 3 * H;
            float w0 = wrow[j], w1 = wrow[H + j], w2 = wrow[2 * H + j];
            #pragma unroll
            for (int r = 0; r < 8; r++) {
                float x = ((const float*)&xv[r])[kk];
                hr[r] += x * w0; hi[r] += x * w1; hn[r] += x * w2;
            }
        }
    }
    #pragma unroll
    for (int r = 0; r < 8; r++) {
        float resetg = 1.f / (1.f + expf(-(gr[r] + hr[r])));
        float inputg = 1.f / (1.f + expf(-(gi[r] + hi[r])));
        float newg = tanhf(gn[r] + resetg * hn[r]);
        float h = h_s[base + r][j];
        h0[(size_t)(bn0 + base + r) * H + j] = newg + inputg * (h - newg);
    }
}

// ---------------------------------------------------------------------------
// K4: seq gather + attention readout -> a[B,H]
// 256 threads: fc2_w staged in LDS once (was re-read per s: 820 MB -> 16 MB),
// s-loop parallelized over 4 waves, cross-wave reduce in LDS.
// grid = B
// ---------------------------------------------------------------------------
__global__ __launch_bounds__(256) void k4_attn(
    const int* __restrict__ alias_in, const int* __restrict__ mask,
    const float* __restrict__ h,
    const float* __restrict__ fc1_w, const float* __restrict__ fc1_b,
    const float* __restrict__ fc2_w, const float* __restrict__ fc2_b,
    const float* __restrict__ fc3_w, float* __restrict__ a)
{
    int tid = threadIdx.x;
    int j = tid & 63, w = tid >> 6;
    int b = blockIdx.x;
    __shared__ __align__(16) float seq_s[S][H];   // 12.8 KB
    __shared__ float f2s[H][H];                   // 16 KB
    __shared__ float q1s[H];
    __shared__ float apart[4][H];
    __shared__ int msum_s;

    for (int idx = tid; idx < S * H; idx += 256) {
        int s = idx >> 6, c = idx & 63;
        int node = alias_in[b * S + s];
        seq_s[s][c] = h[((size_t)b * N + node) * H + c];
    }
    for (int idx = tid; idx < H * H; idx += 256)
        f2s[idx >> 6][idx & 63] = fc2_w[idx];
    if (tid == 0) {
        int m = 0;
        for (int s = 0; s < S; s++) m += mask[b * S + s];
        msum_s = m;
    }
    __syncthreads();

    int last = msum_s - 1;
    if (w == 0) {
        float q1 = fc1_b[j];
        for (int k = 0; k < H; k++) q1 += seq_s[last][k] * fc1_w[k * H + j];
        q1s[j] = q1;
    }
    __syncthreads();

    float f3 = fc3_w[j];
    float q1v = q1s[j];
    float aj = 0.f;
    for (int s = w; s < S; s += 4) {
        float q2 = fc2_b[j];
        #pragma unroll 4
        for (int k4 = 0; k4 < 16; k4++) {
            float4 sv = *(const float4*)&seq_s[s][k4 * 4];   // broadcast
            q2 += sv.x * f2s[k4 * 4 + 0][j] + sv.y * f2s[k4 * 4 + 1][j]
                + sv.z * f2s[k4 * 4 + 2][j] + sv.w * f2s[k4 * 4 + 3][j];
        }
        float v = (1.f / (1.f + expf(-(q1v + q2)))) * f3;
        #pragma unroll
        for (int off = 1; off < 64; off <<= 1) v += __shfl_xor(v, off, 64);
        aj += v * seq_s[s][j] * (float)mask[b * S + s];
    }
    apart[w][j] = aj;
    __syncthreads();
    if (w == 0)
        a[b * H + j] = apart[0][j] + apart[1][j] + apart[2][j] + apart[3][j];
}

// ---------------------------------------------------------------------------
// K5: out[b, v] = dot(a[b,:], emb[v+1,:])  -> [B, VO]
// 128x128 tiles (was 64x64), 8x8 register blocking per thread: LDS bytes per
// FLOP 2.0 -> 1.0 (LDS was the binding resource), emb L2/L3 re-reads 16x->8x.
// LDS 69.6 KB -> 2 blocks/CU. Stride 68 keeps float4 alignment and
// conflict-free / 2-way-free access.
// grid = (ceil(VO/128), B/128), block = 256
// ---------------------------------------------------------------------------
__global__ __launch_bounds__(256) void k5_out(
    const float* __restrict__ a, const float* __restrict__ emb,
    float* __restrict__ out)
{
    __shared__ __align__(16) float As[128][68];
    __shared__ __align__(16) float Es[128][68];
    int tid = threadIdx.x;
    int tx = tid & 15, ty = tid >> 4;
    int v0 = blockIdx.x * 128;
    int b0 = blockIdx.y * 128;

    // cooperative staging: 128 rows x 16 float4 each, coalesced
    for (int idx = tid; idx < 128 * 16; idx += 256) {
        int row = idx >> 4, k4 = idx & 15;
        *(float4*)&As[row][k4 * 4] =
            *(const float4*)(a + (size_t)(b0 + row) * H + k4 * 4);
        int v = v0 + row;
        float4 ev = make_float4(0.f, 0.f, 0.f, 0.f);
        if (v < VO) ev = *(const float4*)(emb + (size_t)(v + 1) * H + k4 * 4);
        *(float4*)&Es[row][k4 * 4] = ev;
    }
    __syncthreads();

    float acc[8][8] = {};
    #pragma unroll 2
    for (int k4 = 0; k4 < 16; k4++) {
        float4 af[8], ef[8];
        #pragma unroll
        for (int i = 0; i < 8; i++)
            af[i] = *(const float4*)&As[ty + 16 * i][k4 * 4];
        #pragma unroll
        for (int jj = 0; jj < 8; jj++)
            ef[jj] = *(const float4*)&Es[tx + 16 * jj][k4 * 4];
        #pragma unroll
        for (int i = 0; i < 8; i++)
            #pragma unroll
            for (int jj = 0; jj < 8; jj++)
                acc[i][jj] += af[i].x * ef[jj].x + af[i].y * ef[jj].y +
                              af[i].z * ef[jj].z + af[i].w * ef[jj].w;
    }

    if (v0 + 128 <= VO) {
        #pragma unroll
        for (int i = 0; i < 8; i++) {
            size_t bofs = (size_t)(b0 + ty + 16 * i) * VO;
            #pragma unroll
            for (int jj = 0; jj < 8; jj++)
                out[bofs + v0 + tx + 16 * jj] = acc[i][jj];
        }
    } else {
        #pragma unroll
        for (int i = 0; i < 8; i++) {
            size_t bofs = (size_t)(b0 + ty + 16 * i) * VO;
            #pragma unroll
            for (int jj = 0; jj < 8; jj++) {
                int v = v0 + tx + 16 * jj;
                if (v < VO) out[bofs + v] = acc[i][jj];
            }
        }
    }
}

// ---------------------------------------------------------------------------
extern "C" void kernel_launch(void* const* d_in, const int* in_sizes, int n_in,
                              void* d_out, int out_size, void* d_ws, size_t ws_size,
                              hipStream_t stream)
{
    const int*   alias_in = (const int*)d_in[0];
    const float* ain      = (const float*)d_in[1];
    const float* aou      = (const float*)d_in[2];
    const int*   items    = (const int*)d_in[3];
    const int*   mask     = (const int*)d_in[4];
    // d_in[5] edge_index: unused
    const float* emb      = (const float*)d_in[6];
    const float* ein_w    = (const float*)d_in[7];
    const float* ein_b    = (const float*)d_in[8];
    const float* eou_w    = (const float*)d_in[9];
    const float* eou_b    = (const float*)d_in[10];
    const float* b_iah    = (const float*)d_in[11];
    const float* b_oah    = (const float*)d_in[12];
    const float* igate_w  = (const float*)d_in[13];
    const float* igate_b  = (const float*)d_in[14];
    const float* hgate_w  = (const float*)d_in[15];
    const float* hgate_b  = (const float*)d_in[16];
    const float* fc1_w    = (const float*)d_in[17];
    const float* fc1_b    = (const float*)d_in[18];
    const float* fc2_w    = (const float*)d_in[19];
    const float* fc2_b    = (const float*)d_in[20];
    const float* fc3_w    = (const float*)d_in[21];

    float* out = (float*)d_out;

    // Intermediates live inside d_out: all dead before K5 rewrites it.
    // 5 x B*N*H floats = 16.4M floats << out_size (204.8M floats).
    const size_t NH = (size_t)B * N * H;
    float* h0     = out;           // overwritten in place by K3 with new h
    float* hv_in  = h0 + NH;
    float* hv_out = hv_in + NH;
    float* in_in  = hv_out + NH;
    float* in_out = in_in + NH;
    float* a      = (float*)d_ws;  // [B,H] must survive K5 -> workspace

    k1_embed_lin<<<(B * N) / 32, 256, 0, stream>>>(items, emb, ein_w, ein_b,
                                                   eou_w, eou_b, h0, hv_in, hv_out);
    k2_adj<<<B, 256, 0, stream>>>(ain, aou, hv_in, hv_out, b_iah, b_oah,
                                  in_in, in_out);
    k3_gru<<<(B * N) / 32, 256, 0, stream>>>(in_in, in_out, igate_w, igate_b,
                                             hgate_w, hgate_b, h0);
    k4_attn<<<B, 256, 0, stream>>>(alias_in, mask, h0, fc1_w, fc1_b,
                                   fc2_w, fc2_b, fc3_w, a);
    dim3 g5((VO + 127) / 128, B / 128);
    k5_out<<<g5, 256, 0, stream>>>(a, emb, out);
}

// Round 2
// 1314.135 us; speedup vs baseline: 1.1886x; 1.0755x over previous
//
#include <hip/hip_runtime.h>
#include <math.h>

#define H 64
#define N 50
#define S 50
#define B 1024
#define V 200000
#define VO (V - 1)   // 199999 output columns

typedef __attribute__((ext_vector_type(8))) short short8v;   // bf16x8 frag (4 VGPR)
typedef __attribute__((ext_vector_type(4))) short short4v;   // bf16x4 (8B LDS write)
typedef __attribute__((ext_vector_type(4))) float f32x4;     // MFMA acc

// fp32 -> bf16 round-to-nearest-even (inputs finite)
__device__ __forceinline__ unsigned short f2bf(float x) {
    union { float f; unsigned int u; } c; c.f = x;
    unsigned int u = c.u + (0x7fffu + ((c.u >> 16) & 1u));
    return (unsigned short)(u >> 16);
}
__device__ __forceinline__ float bf2f(unsigned short h) {
    union { float f; unsigned int u; } c; c.u = ((unsigned int)h) << 16;
    return c.f;
}

// ---------------------------------------------------------------------------
// K1: h0 = emb[items]; hv_in = h0@ein_w + ein_b; hv_out = h0@eou_w + eou_b
// ---------------------------------------------------------------------------
__global__ __launch_bounds__(256) void k1_embed_lin(
    const int* __restrict__ items, const float* __restrict__ emb,
    const float* __restrict__ ein_w, const float* __restrict__ ein_b,
    const float* __restrict__ eou_w, const float* __restrict__ eou_b,
    float* __restrict__ h0, float* __restrict__ hv_in, float* __restrict__ hv_out)
{
    int tid = threadIdx.x;
    int j = tid & 63, w = tid >> 6;
    int bn0 = blockIdx.x * 32;
    __shared__ __align__(16) float hs[32][H];   // 8 KB

    for (int idx = tid; idx < 32 * H; idx += 256) {
        int row = idx >> 6, col = idx & 63;
        int item = items[bn0 + row];
        float hv = emb[(size_t)item * H + col];
        hs[row][col] = hv;
        h0[(size_t)(bn0 + row) * H + col] = hv;
    }
    __syncthreads();

    float accI[8], accO[8];
    {
        float bi = ein_b[j], bo = eou_b[j];
        #pragma unroll
        for (int r = 0; r < 8; r++) { accI[r] = bi; accO[r] = bo; }
    }
    int base = w * 8;
    #pragma unroll 4
    for (int k4 = 0; k4 < 16; k4++) {
        float4 xv[8];
        #pragma unroll
        for (int r = 0; r < 8; r++)
            xv[r] = *(const float4*)&hs[base + r][k4 * 4];  // broadcast, free
        #pragma unroll
        for (int kk = 0; kk < 4; kk++) {
            int k = k4 * 4 + kk;
            float wi = ein_w[k * H + j];   // coalesced 256B across lanes
            float wo = eou_w[k * H + j];
            #pragma unroll
            for (int r = 0; r < 8; r++) {
                float x = ((const float*)&xv[r])[kk];
                accI[r] += x * wi;
                accO[r] += x * wo;
            }
        }
    }
    #pragma unroll
    for (int r = 0; r < 8; r++) {
        hv_in [(size_t)(bn0 + base + r) * H + j] = accI[r];
        hv_out[(size_t)(bn0 + base + r) * H + j] = accO[r];
    }
}

// ---------------------------------------------------------------------------
// K2: input_in = ain @ hv_in + b_iah ; input_out = aou @ hv_out + b_oah
// ---------------------------------------------------------------------------
__global__ __launch_bounds__(256) void k2_adj(
    const float* __restrict__ ain, const float* __restrict__ aou,
    const float* __restrict__ hv_in, const float* __restrict__ hv_out,
    const float* __restrict__ b_iah, const float* __restrict__ b_oah,
    float* __restrict__ in_in, float* __restrict__ in_out)
{
    int tid = threadIdx.x;
    int j = tid & 63, w = tid >> 6;
    int b = blockIdx.x;
    __shared__ float hin_s[N][H];   // 12.8 KB
    __shared__ float hou_s[N][H];   // 12.8 KB

    for (int idx = tid; idx < N * H; idx += 256) {
        int row = idx >> 6, col = idx & 63;
        hin_s[row][col] = hv_in [((size_t)b * N + row) * H + col];
        hou_s[row][col] = hv_out[((size_t)b * N + row) * H + col];
    }
    __syncthreads();

    float bi = b_iah[j], bo = b_oah[j];
    for (int n = w; n < N; n += 4) {
        const float* ar = ain + ((size_t)b * N + n) * N;
        const float* br = aou + ((size_t)b * N + n) * N;
        float si = bi, so = bo;
        for (int m = 0; m < N; m++) {
            si += ar[m] * hin_s[m][j];
            so += br[m] * hou_s[m][j];
        }
        in_in [((size_t)b * N + n) * H + j] = si;
        in_out[((size_t)b * N + n) * H + j] = so;
    }
}

// ---------------------------------------------------------------------------
// K3: GRU gates. 4 waves x 8 rows register-blocked.
// ---------------------------------------------------------------------------
__global__ __launch_bounds__(256) void k3_gru(
    const float* __restrict__ in_in, const float* __restrict__ in_out,
    const float* __restrict__ igate_w, const float* __restrict__ igate_b,
    const float* __restrict__ hgate_w, const float* __restrict__ hgate_b,
    float* __restrict__ h0)
{
    int tid = threadIdx.x;
    int j = tid & 63, w = tid >> 6;
    int bn0 = blockIdx.x * 32;
    __shared__ __align__(16) float inp_s[32][2 * H];   // 16 KB
    __shared__ __align__(16) float h_s[32][H];         // 8 KB

    for (int idx = tid; idx < 32 * H; idx += 256) {
        int row = idx >> 6, col = idx & 63;
        size_t g = (size_t)(bn0 + row) * H + col;
        inp_s[row][col]     = in_in[g];
        inp_s[row][H + col] = in_out[g];
        h_s[row][col]       = h0[g];
    }
    __syncthreads();

    int base = w * 8;
    float gr[8], gi[8], gn[8];
    {
        float b0v = igate_b[j], b1v = igate_b[H + j], b2v = igate_b[2 * H + j];
        #pragma unroll
        for (int r = 0; r < 8; r++) { gr[r] = b0v; gi[r] = b1v; gn[r] = b2v; }
    }
    #pragma unroll 2
    for (int k4 = 0; k4 < 32; k4++) {          // 2H = 128 k's
        float4 xv[8];
        #pragma unroll
        for (int r = 0; r < 8; r++)
            xv[r] = *(const float4*)&inp_s[base + r][k4 * 4];
        #pragma unroll
        for (int kk = 0; kk < 4; kk++) {
            int k = k4 * 4 + kk;
            const float* wrow = igate_w + (size_t)k * 3 * H;
            float w0 = wrow[j], w1 = wrow[H + j], w2 = wrow[2 * H + j];
            #pragma unroll
            for (int r = 0; r < 8; r++) {
                float x = ((const float*)&xv[r])[kk];
                gr[r] += x * w0; gi[r] += x * w1; gn[r] += x * w2;
            }
        }
    }
    float hr[8], hi[8], hn[8];
    {
        float b0v = hgate_b[j], b1v = hgate_b[H + j], b2v = hgate_b[2 * H + j];
        #pragma unroll
        for (int r = 0; r < 8; r++) { hr[r] = b0v; hi[r] = b1v; hn[r] = b2v; }
    }
    #pragma unroll 2
    for (int k4 = 0; k4 < 16; k4++) {          // H = 64 k's
        float4 xv[8];
        #pragma unroll
        for (int r = 0; r < 8; r++)
            xv[r] = *(const float4*)&h_s[base + r][k4 * 4];
        #pragma unroll
        for (int kk = 0; kk < 4; kk++) {
            int k = k4 * 4 + kk;
            const float* wrow = hgate_w + (size_t)k * 3 * H;
            float w0 = wrow[j], w1 = wrow[H + j], w2 = wrow[2 * H + j];
            #pragma unroll
            for (int r = 0; r < 8; r++) {
                float x = ((const float*)&xv[r])[kk];
                hr[r] += x * w0; hi[r] += x * w1; hn[r] += x * w2;
            }
        }
    }
    #pragma unroll
    for (int r = 0; r < 8; r++) {
        float resetg = 1.f / (1.f + expf(-(gr[r] + hr[r])));
        float inputg = 1.f / (1.f + expf(-(gi[r] + hi[r])));
        float newg = tanhf(gn[r] + resetg * hn[r]);
        float h = h_s[base + r][j];
        h0[(size_t)(bn0 + base + r) * H + j] = newg + inputg * (h - newg);
    }
}

// ---------------------------------------------------------------------------
// K4: seq gather + attention readout -> a[B,H]
// ---------------------------------------------------------------------------
__global__ __launch_bounds__(256) void k4_attn(
    const int* __restrict__ alias_in, const int* __restrict__ mask,
    const float* __restrict__ h,
    const float* __restrict__ fc1_w, const float* __restrict__ fc1_b,
    const float* __restrict__ fc2_w, const float* __restrict__ fc2_b,
    const float* __restrict__ fc3_w, float* __restrict__ a)
{
    int tid = threadIdx.x;
    int j = tid & 63, w = tid >> 6;
    int b = blockIdx.x;
    __shared__ __align__(16) float seq_s[S][H];   // 12.8 KB
    __shared__ float f2s[H][H];                   // 16 KB
    __shared__ float q1s[H];
    __shared__ float apart[4][H];
    __shared__ int msum_s;

    for (int idx = tid; idx < S * H; idx += 256) {
        int s = idx >> 6, c = idx & 63;
        int node = alias_in[b * S + s];
        seq_s[s][c] = h[((size_t)b * N + node) * H + c];
    }
    for (int idx = tid; idx < H * H; idx += 256)
        f2s[idx >> 6][idx & 63] = fc2_w[idx];
    if (tid == 0) {
        int m = 0;
        for (int s = 0; s < S; s++) m += mask[b * S + s];
        msum_s = m;
    }
    __syncthreads();

    int last = msum_s - 1;
    if (w == 0) {
        float q1 = fc1_b[j];
        for (int k = 0; k < H; k++) q1 += seq_s[last][k] * fc1_w[k * H + j];
        q1s[j] = q1;
    }
    __syncthreads();

    float f3 = fc3_w[j];
    float q1v = q1s[j];
    float aj = 0.f;
    for (int s = w; s < S; s += 4) {
        float q2 = fc2_b[j];
        #pragma unroll 4
        for (int k4 = 0; k4 < 16; k4++) {
            float4 sv = *(const float4*)&seq_s[s][k4 * 4];   // broadcast
            q2 += sv.x * f2s[k4 * 4 + 0][j] + sv.y * f2s[k4 * 4 + 1][j]
                + sv.z * f2s[k4 * 4 + 2][j] + sv.w * f2s[k4 * 4 + 3][j];
        }
        float v = (1.f / (1.f + expf(-(q1v + q2)))) * f3;
        #pragma unroll
        for (int off = 1; off < 64; off <<= 1) v += __shfl_xor(v, off, 64);
        aj += v * seq_s[s][j] * (float)mask[b * S + s];
    }
    apart[w][j] = aj;
    __syncthreads();
    if (w == 0)
        a[b * H + j] = apart[0][j] + apart[1][j] + apart[2][j] + apart[3][j];
}

// ---------------------------------------------------------------------------
// K5: out[b, v] = dot(a[b,:], emb[v+1,:])  -> [B, VO]
// MFMA bf16 hi/lo split-precision (Ah*Eh + Al*Eh + Ah*El): fp32-grade accuracy
// at matrix-core rate. Block tile 128v x 128b, 4 waves in 2x2, each wave 64x64
// via 4x4 fragments of mfma_f32_16x16x32_bf16 (6 K-steps = 192 effective K).
// LDS: A and E tiles as [row][Khi(64) | Klo(64)] bf16, row stride 136 shorts
// (272 B: same stride class as the fp32 version that measured 0 conflicts).
// New floor: HBM write of out (819 MB ~ 130 us).
// grid = (ceil(VO/128), B/128), block = 256
// ---------------------------------------------------------------------------
__global__ __launch_bounds__(256) void k5_out(
    const float* __restrict__ a, const float* __restrict__ emb,
    float* __restrict__ out)
{
    __shared__ short As[128][136];   // 34.8 KB  (bf16 bits)
    __shared__ short Es[128][136];   // 34.8 KB
    int tid = threadIdx.x;
    int v0 = blockIdx.x * 128;
    int b0 = blockIdx.y * 128;

    // --- stage + convert: 128 rows x 16 float4 per operand, 8 per thread ---
    for (int idx = tid; idx < 128 * 16; idx += 256) {
        int row = idx >> 4, k4 = idx & 15;   // k = k4*4 .. k4*4+3
        // A (always valid rows)
        float4 av = *(const float4*)(a + (size_t)(b0 + row) * H + k4 * 4);
        {
            unsigned short h0b = f2bf(av.x), h1b = f2bf(av.y),
                           h2b = f2bf(av.z), h3b = f2bf(av.w);
            short4v hi = { (short)h0b, (short)h1b, (short)h2b, (short)h3b };
            short4v lo = { (short)f2bf(av.x - bf2f(h0b)),
                           (short)f2bf(av.y - bf2f(h1b)),
                           (short)f2bf(av.z - bf2f(h2b)),
                           (short)f2bf(av.w - bf2f(h3b)) };
            *(short4v*)&As[row][k4 * 4]      = hi;
            *(short4v*)&As[row][64 + k4 * 4] = lo;
        }
        // E (guard tail rows)
        int v = v0 + row;
        float4 ev = make_float4(0.f, 0.f, 0.f, 0.f);
        if (v < VO) ev = *(const float4*)(emb + (size_t)(v + 1) * H + k4 * 4);
        {
            unsigned short h0b = f2bf(ev.x), h1b = f2bf(ev.y),
                           h2b = f2bf(ev.z), h3b = f2bf(ev.w);
            short4v hi = { (short)h0b, (short)h1b, (short)h2b, (short)h3b };
            short4v lo = { (short)f2bf(ev.x - bf2f(h0b)),
                           (short)f2bf(ev.y - bf2f(h1b)),
                           (short)f2bf(ev.z - bf2f(h2b)),
                           (short)f2bf(ev.w - bf2f(h3b)) };
            *(short4v*)&Es[row][k4 * 4]      = hi;
            *(short4v*)&Es[row][64 + k4 * 4] = lo;
        }
    }
    __syncthreads();

    // --- MFMA main: wave (wb,wv) owns 64b x 64v ---
    int lane = tid & 63, wid = tid >> 6;
    int wv = wid & 1, wb = wid >> 1;
    int lr = lane & 15, lk = lane >> 4;          // frag row/col, k-subgroup
    const short* Ab = &As[wb * 64 + lr][lk * 8];
    const short* Eb = &Es[wv * 64 + lr][lk * 8];

    f32x4 acc[4][4] = {};

#define KSTEP(AH, AK, EH, EK)                                                  \
    do {                                                                       \
        short8v af[4], ef[4];                                                  \
        _Pragma("unroll")                                                      \
        for (int i = 0; i < 4; i++)                                            \
            af[i] = *(const short8v*)(Ab + i * 16 * 136 + (AH) * 64 + (AK) * 32); \
        _Pragma("unroll")                                                      \
        for (int jj = 0; jj < 4; jj++)                                         \
            ef[jj] = *(const short8v*)(Eb + jj * 16 * 136 + (EH) * 64 + (EK) * 32); \
        _Pragma("unroll")                                                      \
        for (int i = 0; i < 4; i++)                                            \
            _Pragma("unroll")                                                  \
            for (int jj = 0; jj < 4; jj++)                                     \
                acc[i][jj] = __builtin_amdgcn_mfma_f32_16x16x32_bf16(          \
                    af[i], ef[jj], acc[i][jj], 0, 0, 0);                       \
    } while (0)

    // Ah*Eh (K=64) + Al*Eh (K=64) + Ah*El (K=64); lo*lo dropped (~2^-18 rel)
    KSTEP(0, 0, 0, 0);
    KSTEP(0, 1, 0, 1);
    KSTEP(1, 0, 0, 0);
    KSTEP(1, 1, 0, 1);
    KSTEP(0, 0, 1, 0);
    KSTEP(0, 1, 1, 1);
#undef KSTEP

    // --- store: C/D layout col=lane&15, row=(lane>>4)*4+reg ---
    if (v0 + 128 <= VO) {
        #pragma unroll
        for (int i = 0; i < 4; i++) {
            int brow = b0 + wb * 64 + i * 16 + lk * 4;
            #pragma unroll
            for (int r = 0; r < 4; r++) {
                size_t ofs = (size_t)(brow + r) * VO + v0 + wv * 64 + lr;
                #pragma unroll
                for (int jj = 0; jj < 4; jj++)
                    out[ofs + jj * 16] = acc[i][jj][r];
            }
        }
    } else {
        #pragma unroll
        for (int i = 0; i < 4; i++) {
            int brow = b0 + wb * 64 + i * 16 + lk * 4;
            #pragma unroll
            for (int r = 0; r < 4; r++) {
                size_t ofs = (size_t)(brow + r) * VO;
                #pragma unroll
                for (int jj = 0; jj < 4; jj++) {
                    int v = v0 + wv * 64 + jj * 16 + lr;
                    if (v < VO) out[ofs + v] = acc[i][jj][r];
                }
            }
        }
    }
}

// ---------------------------------------------------------------------------
extern "C" void kernel_launch(void* const* d_in, const int* in_sizes, int n_in,
                              void* d_out, int out_size, void* d_ws, size_t ws_size,
                              hipStream_t stream)
{
    const int*   alias_in = (const int*)d_in[0];
    const float* ain      = (const float*)d_in[1];
    const float* aou      = (const float*)d_in[2];
    const int*   items    = (const int*)d_in[3];
    const int*   mask     = (const int*)d_in[4];
    // d_in[5] edge_index: unused
    const float* emb      = (const float*)d_in[6];
    const float* ein_w    = (const float*)d_in[7];
    const float* ein_b    = (const float*)d_in[8];
    const float* eou_w    = (const float*)d_in[9];
    const float* eou_b    = (const float*)d_in[10];
    const float* b_iah    = (const float*)d_in[11];
    const float* b_oah    = (const float*)d_in[12];
    const float* igate_w  = (const float*)d_in[13];
    const float* igate_b  = (const float*)d_in[14];
    const float* hgate_w  = (const float*)d_in[15];
    const float* hgate_b  = (const float*)d_in[16];
    const float* fc1_w    = (const float*)d_in[17];
    const float* fc1_b    = (const float*)d_in[18];
    const float* fc2_w    = (const float*)d_in[19];
    const float* fc2_b    = (const float*)d_in[20];
    const float* fc3_w    = (const float*)d_in[21];

    float* out = (float*)d_out;

    // Intermediates live inside d_out: all dead before K5 rewrites it.
    const size_t NH = (size_t)B * N * H;
    float* h0     = out;           // overwritten in place by K3 with new h
    float* hv_in  = h0 + NH;
    float* hv_out = hv_in + NH;
    float* in_in  = hv_out + NH;
    float* in_out = in_in + NH;
    float* a      = (float*)d_ws;  // [B,H] must survive K5 -> workspace

    k1_embed_lin<<<(B * N) / 32, 256, 0, stream>>>(items, emb, ein_w, ein_b,
                                                   eou_w, eou_b, h0, hv_in, hv_out);
    k2_adj<<<B, 256, 0, stream>>>(ain, aou, hv_in, hv_out, b_iah, b_oah,
                                  in_in, in_out);
    k3_gru<<<(B * N) / 32, 256, 0, stream>>>(in_in, in_out, igate_w, igate_b,
                                             hgate_w, hgate_b, h0);
    k4_attn<<<B, 256, 0, stream>>>(alias_in, mask, h0, fc1_w, fc1_b,
                                   fc2_w, fc2_b, fc3_w, a);
    dim3 g5((VO + 127) / 128, B / 128);
    k5_out<<<g5, 256, 0, stream>>>(a, emb, out);
}